// Round 1
// baseline (54.551 us; speedup 1.0000x reference)
//
#include <hip/hip_runtime.h>

#define TILE_W 64
#define TILE_H 16
#define HALO 5
#define RAW_H (TILE_H + 2*HALO)   // 26
#define RAW_W (TILE_W + 2*HALO)   // 74
#define RAW_S 76                  // padded stride
#define IMG_H 512
#define IMG_W 512
#define NBATCH 32

__device__ __forceinline__ float nan0(float v) { return v == v ? v : 0.0f; }

__global__ __launch_bounds__(256)
void simplenet_fused(const float* __restrict__ X,
                     const float* __restrict__ w0, const float* __restrict__ b0,
                     const float* __restrict__ w1, const float* __restrict__ w2,
                     const float* __restrict__ w3, const float* __restrict__ w4,
                     const float* __restrict__ w5, const float* __restrict__ w6,
                     float* __restrict__ out)
{
    __shared__ float RAW[RAW_H][RAW_S];
    __shared__ float TA[RAW_H][TILE_W];
    __shared__ float TB[RAW_H][TILE_W];

    const int tid = threadIdx.x;
    const int tx0 = blockIdx.x * TILE_W;
    const int ty0 = blockIdx.y * TILE_H;
    const int b   = blockIdx.z;

    const float* Xb = X + (size_t)b * (IMG_H * IMG_W);

    // Stage tile + halo. Out-of-image = NaN sentinel:
    //  - pools use fminf/fmaxf which ignore NaN  (== -inf/+inf padding)
    //  - convs apply nan0() per tap              (== zero padding)
    for (int idx = tid; idx < RAW_H * RAW_W; idx += 256) {
        const int r = idx / RAW_W;
        const int c = idx - r * RAW_W;
        const int gy = ty0 - HALO + r;
        const int gx = tx0 - HALO + c;
        float v = __builtin_nanf("");
        if (gy >= 0 && gy < IMG_H && gx >= 0 && gx < IMG_W)
            v = Xb[gy * IMG_W + gx];
        RAW[r][c] = v;
    }

    // 1x1 conv weights (scalars per output channel)
    const float W0c0 = w0[0], W0c1 = w0[1];
    const float B0   = b0[0], B1   = b0[1];
    const float W1c0 = w1[0], W1c1 = w1[1];
    const float W2c0 = w2[0], W2c1 = w2[1];
    const float W3c0 = w3[0], W3c1 = w3[1];
    const float W4c0 = w4[0], W4c1 = w4[1];
    const float W5c0 = w5[0], W5c1 = w5[1];
    const float W6c0 = w6[0], W6c1 = w6[1];

    __syncthreads();

    const int xo = tid & 63;   // output col within tile
    const int yb = tid >> 6;   // 0..3; rows yb, yb+4, yb+8, yb+12

    float a0[4], a1[4];
#pragma unroll
    for (int p = 0; p < 4; ++p) { a0[p] = B0; a1[p] = B1; }

    // identity + 3x3 cross blur (4 taps), straight from RAW
#pragma unroll
    for (int p = 0; p < 4; ++p) {
        const int yr = yb + 4*p + HALO, xc = xo + HALO;
        const float x  = RAW[yr][xc];
        const float cr = 0.25f * (nan0(RAW[yr-1][xc]) + nan0(RAW[yr+1][xc])
                                + nan0(RAW[yr][xc-1]) + nan0(RAW[yr][xc+1]));
        a0[p] += W0c0 * x + W1c0 * cr;
        a1[p] += W0c1 * x + W1c1 * cr;
    }

    // 7x7 gaussian, separable (outer product of normalized 1D == normalized 2D)
    const float G[7] = {0.10628875f, 0.14032194f, 0.16577342f, 0.17523179f,
                        0.16577342f, 0.14032194f, 0.10628875f};

    for (int idx = tid; idx < RAW_H * TILE_W; idx += 256) {
        const int r = idx >> 6;
        const int c = idx & 63;
        float s = 0.f;
#pragma unroll
        for (int k = 0; k < 7; ++k) s += G[k] * nan0(RAW[r][c + 2 + k]);
        TA[r][c] = s;
    }
    __syncthreads();
#pragma unroll
    for (int p = 0; p < 4; ++p) {
        const int yo = yb + 4*p;
        float s = 0.f;
#pragma unroll
        for (int k = 0; k < 7; ++k) s += G[k] * TA[yo + 2 + k][xo];
        a0[p] += W2c0 * s;
        a1[p] += W2c1 * s;
    }
    __syncthreads();

    // 3x3 min/max pool, separable
    for (int idx = tid; idx < RAW_H * TILE_W; idx += 256) {
        const int r = idx >> 6;
        const int c = idx & 63;
        const float v0 = RAW[r][c+4], v1 = RAW[r][c+5], v2 = RAW[r][c+6];
        TA[r][c] = fminf(fminf(v0, v1), v2);
        TB[r][c] = fmaxf(fmaxf(v0, v1), v2);
    }
    __syncthreads();
#pragma unroll
    for (int p = 0; p < 4; ++p) {
        const int yo = yb + 4*p;
        float mn = TA[yo+4][xo];
        mn = fminf(mn, TA[yo+5][xo]);
        mn = fminf(mn, TA[yo+6][xo]);
        float mx = TB[yo+4][xo];
        mx = fmaxf(mx, TB[yo+5][xo]);
        mx = fmaxf(mx, TB[yo+6][xo]);
        a0[p] += W3c0 * mn + W5c0 * mx;
        a1[p] += W3c1 * mn + W5c1 * mx;
    }
    __syncthreads();

    // 11x11 min/max pool, separable
    for (int idx = tid; idx < RAW_H * TILE_W; idx += 256) {
        const int r = idx >> 6;
        const int c = idx & 63;
        float mn = RAW[r][c], mx = mn;
#pragma unroll
        for (int k = 1; k < 11; ++k) {
            const float v = RAW[r][c + k];
            mn = fminf(mn, v);
            mx = fmaxf(mx, v);
        }
        TA[r][c] = mn;
        TB[r][c] = mx;
    }
    __syncthreads();
#pragma unroll
    for (int p = 0; p < 4; ++p) {
        const int yo = yb + 4*p;
        float mn = TA[yo][xo], mx = TB[yo][xo];
#pragma unroll
        for (int k = 1; k < 11; ++k) {
            mn = fminf(mn, TA[yo + k][xo]);
            mx = fmaxf(mx, TB[yo + k][xo]);
        }
        a0[p] += W4c0 * mn + W6c0 * mx;
        a1[p] += W4c1 * mn + W6c1 * mx;
    }

    // store both output channel planes
    float* out0 = out + ((size_t)b * 2 + 0) * (IMG_H * IMG_W);
    float* out1 = out + ((size_t)b * 2 + 1) * (IMG_H * IMG_W);
#pragma unroll
    for (int p = 0; p < 4; ++p) {
        const int gy = ty0 + yb + 4*p;
        const int gx = tx0 + xo;
        out0[gy * IMG_W + gx] = a0[p];
        out1[gy * IMG_W + gx] = a1[p];
    }
}

extern "C" void kernel_launch(void* const* d_in, const int* in_sizes, int n_in,
                              void* d_out, int out_size, void* d_ws, size_t ws_size,
                              hipStream_t stream) {
    const float* X  = (const float*)d_in[0];
    const float* w0 = (const float*)d_in[1];
    const float* b0 = (const float*)d_in[2];
    const float* w1 = (const float*)d_in[3];
    const float* w2 = (const float*)d_in[4];
    const float* w3 = (const float*)d_in[5];
    const float* w4 = (const float*)d_in[6];
    const float* w5 = (const float*)d_in[7];
    const float* w6 = (const float*)d_in[8];
    float* out = (float*)d_out;

    dim3 grid(IMG_W / TILE_W, IMG_H / TILE_H, NBATCH);
    simplenet_fused<<<grid, 256, 0, stream>>>(X, w0, b0, w1, w2, w3, w4, w5, w6, out);
}